// Round 14
// baseline (388.078 us; speedup 1.0000x reference)
//
#include <hip/hip_runtime.h>

#define N_NODES 100000
#define N_EDGES 1600000
#define DIM 5
#define HID 64
#define N_LAYERS 3
#define SCAN_BLK 256
#define NBLK ((N_NODES + SCAN_BLK - 1) / SCAN_BLK)   // 391

// ================= fused: histogram + layer-1 edge MLP (original order) ====
// The atomicAdd is issued FIRST; the 1024-FMA message MLP is independent of
// its result, so the VALU work hides under the ~24 Gops/s atomic wall.
__global__ __launch_bounds__(256) void fused_hist_msg1_kernel(
    const float* __restrict__ x,
    const int* __restrict__ ei,          // [2][E]
    const float* __restrict__ W1, const float* __restrict__ b1,
    const float* __restrict__ W2, const float* __restrict__ b2,
    int* __restrict__ cnt, int* __restrict__ rank,
    float* __restrict__ msg0)            // [E][5], original edge order
{
    int e = blockIdx.x * blockDim.x + threadIdx.x;
    if (e >= N_EDGES) return;
    int src = ei[e];
    int dst = ei[N_EDGES + e];

    int rk = atomicAdd(&cnt[dst], 1);    // in flight during MLP below

    float in[10];
    const float* xi = x + (long)dst * DIM;
    const float* xj = x + (long)src * DIM;
#pragma unroll
    for (int d = 0; d < DIM; ++d) in[d] = xi[d];
#pragma unroll
    for (int d = 0; d < DIM; ++d) in[DIM + d] = xj[d];

    float msg[DIM];
#pragma unroll
    for (int j = 0; j < DIM; ++j) msg[j] = b2[j];

#pragma unroll 8
    for (int h = 0; h < HID; ++h) {
        float acc = b1[h];
#pragma unroll
        for (int d = 0; d < 10; ++d) acc = fmaf(in[d], W1[d * HID + h], acc);
        acc = fmaxf(acc, 0.0f);
#pragma unroll
        for (int j = 0; j < DIM; ++j) msg[j] = fmaf(acc, W2[h * DIM + j], msg[j]);
    }

    float* mp = msg0 + (long)e * DIM;
#pragma unroll
    for (int j = 0; j < DIM; ++j) mp[j] = msg[j];

    rank[e] = rk;                        // atomic result consumed last
}

// ================= CSR scan =================

__global__ __launch_bounds__(SCAN_BLK) void scan_part_kernel(
    const int* __restrict__ cnt, int* __restrict__ blk_sum)
{
    __shared__ int s[SCAN_BLK];
    int t = threadIdx.x;
    int i = blockIdx.x * SCAN_BLK + t;
    s[t] = (i < N_NODES) ? cnt[i] : 0;
    __syncthreads();
    for (int off = SCAN_BLK / 2; off > 0; off >>= 1) {
        if (t < off) s[t] += s[t + off];
        __syncthreads();
    }
    if (t == 0) blk_sum[blockIdx.x] = s[0];
}

__global__ __launch_bounds__(512) void scan_blk_kernel(
    const int* __restrict__ blk_sum, int* __restrict__ blk_pref)
{
    __shared__ int s[512];
    int t = threadIdx.x;
    int v = (t < NBLK) ? blk_sum[t] : 0;
    s[t] = v;
    __syncthreads();
    for (int off = 1; off < 512; off <<= 1) {
        int a = (t >= off) ? s[t - off] : 0;
        __syncthreads();
        s[t] += a;
        __syncthreads();
    }
    if (t < NBLK) blk_pref[t] = s[t] - v;   // exclusive prefix
}

__global__ __launch_bounds__(SCAN_BLK) void scan_add_kernel(
    const int* __restrict__ cnt, const int* __restrict__ blk_pref,
    int* __restrict__ row_ptr)
{
    __shared__ int s[SCAN_BLK];
    int t = threadIdx.x;
    int i = blockIdx.x * SCAN_BLK + t;
    int c = (i < N_NODES) ? cnt[i] : 0;
    s[t] = c;
    __syncthreads();
    for (int off = 1; off < SCAN_BLK; off <<= 1) {
        int a = (t >= off) ? s[t - off] : 0;
        __syncthreads();
        s[t] += a;
        __syncthreads();
    }
    if (i < N_NODES) row_ptr[i] = blk_pref[blockIdx.x] + s[t] - c;
    if (i == 0) row_ptr[N_NODES] = N_EDGES;
}

// scatter: spair[pos] = {src,dst} (layers 2,3) and eperm[pos] = e (layer-1 gather)
__global__ __launch_bounds__(256) void scatter_pair_perm_kernel(
    const int* __restrict__ ei, const int* __restrict__ rank,
    const int* __restrict__ row_ptr,
    int2* __restrict__ spair, int* __restrict__ eperm)
{
    int e = blockIdx.x * blockDim.x + threadIdx.x;
    if (e >= N_EDGES) return;
    int src = ei[e];
    int dst = ei[N_EDGES + e];
    int pos = row_ptr[dst] + rank[e];
    spair[pos] = make_int2(src, dst);
    eperm[pos] = e;
}

// ================= per-layer kernels =================

// msg = relu([x_dst, x_src] @ W1 + b1) @ W2 + b2, sorted order (layers 2,3)
__global__ __launch_bounds__(256) void edge_msg_sorted_kernel(
    const float* __restrict__ x,
    const int2* __restrict__ spair,
    const float* __restrict__ W1, const float* __restrict__ b1,
    const float* __restrict__ W2, const float* __restrict__ b2,
    float* __restrict__ msg_buf)
{
    int e = blockIdx.x * blockDim.x + threadIdx.x;
    if (e >= N_EDGES) return;
    int2 p = spair[e];          // p.x = src, p.y = dst

    float in[10];
    const float* xi = x + (long)p.y * DIM;
    const float* xj = x + (long)p.x * DIM;
#pragma unroll
    for (int d = 0; d < DIM; ++d) in[d] = xi[d];
#pragma unroll
    for (int d = 0; d < DIM; ++d) in[DIM + d] = xj[d];

    float msg[DIM];
#pragma unroll
    for (int j = 0; j < DIM; ++j) msg[j] = b2[j];

#pragma unroll 8
    for (int h = 0; h < HID; ++h) {
        float acc = b1[h];
#pragma unroll
        for (int d = 0; d < 10; ++d) acc = fmaf(in[d], W1[d * HID + h], acc);
        acc = fmaxf(acc, 0.0f);
#pragma unroll
        for (int j = 0; j < DIM; ++j) msg[j] = fmaf(acc, W2[h * DIM + j], msg[j]);
    }

    float* mp = msg_buf + (long)e * DIM;
#pragma unroll
    for (int j = 0; j < DIM; ++j) mp[j] = msg[j];
}

// 8 lanes per node; INDIRECT: msg read via eperm (layer 1, original-order msg0)
template <bool FINAL, bool INDIRECT>
__global__ __launch_bounds__(256) void gather_update8_kernel(
    const float* __restrict__ x,
    const float* __restrict__ msg_buf,
    const int* __restrict__ eperm,
    const int* __restrict__ row_ptr,
    const float* __restrict__ U1, const float* __restrict__ bu1,
    const float* __restrict__ U2, const float* __restrict__ bu2,
    const float* __restrict__ Wr, const float* __restrict__ br,
    float* __restrict__ xout)
{
    int gt = blockIdx.x * blockDim.x + threadIdx.x;   // 800000 threads exactly
    int v = gt >> 3;
    int r = gt & 7;
    if (v >= N_NODES) return;

    int s = row_ptr[v], e1 = row_ptr[v + 1];

    float agg[DIM] = {0.f, 0.f, 0.f, 0.f, 0.f};
    for (int e = s + r; e < e1; e += 8) {
        long me = INDIRECT ? (long)eperm[e] : (long)e;
        const float* mp = msg_buf + me * DIM;
#pragma unroll
        for (int j = 0; j < DIM; ++j) agg[j] += mp[j];
    }
#pragma unroll
    for (int m = 1; m < 8; m <<= 1) {
#pragma unroll
        for (int j = 0; j < DIM; ++j) agg[j] += __shfl_xor(agg[j], m, 64);
    }

    float in2[10];
#pragma unroll
    for (int d = 0; d < DIM; ++d) in2[d] = x[(long)v * DIM + d];
#pragma unroll
    for (int d = 0; d < DIM; ++d) in2[DIM + d] = agg[d];

    float upd[DIM] = {0.f, 0.f, 0.f, 0.f, 0.f};
#pragma unroll
    for (int hh = 0; hh < 8; ++hh) {
        int h = r + hh * 8;
        float acc = bu1[h];
#pragma unroll
        for (int d = 0; d < 10; ++d) acc = fmaf(in2[d], U1[d * HID + h], acc);
        acc = fmaxf(acc, 0.0f);
#pragma unroll
        for (int j = 0; j < DIM; ++j) upd[j] = fmaf(acc, U2[h * DIM + j], upd[j]);
    }
#pragma unroll
    for (int m = 1; m < 8; m <<= 1) {
#pragma unroll
        for (int j = 0; j < DIM; ++j) upd[j] += __shfl_xor(upd[j], m, 64);
    }

    if (r == 0) {
        float xn[DIM];
#pragma unroll
        for (int j = 0; j < DIM; ++j) xn[j] = upd[j] + bu2[j] + in2[j];
        if (FINAL) {
#pragma unroll
            for (int j = 0; j < DIM; ++j) {
                float o = br[j];
#pragma unroll
                for (int d = 0; d < DIM; ++d) o = fmaf(xn[d], Wr[d * DIM + j], o);
                xout[(long)v * DIM + j] = o;
            }
        } else {
#pragma unroll
            for (int j = 0; j < DIM; ++j) xout[(long)v * DIM + j] = xn[j];
        }
    }
}

// ================= fallback (round-3 atomic path) =================

__global__ __launch_bounds__(256) void edge_msg_kernel(
    const float* __restrict__ x, const int* __restrict__ ei,
    const float* __restrict__ W1, const float* __restrict__ b1,
    const float* __restrict__ W2, const float* __restrict__ b2,
    float* __restrict__ aggr)
{
    int e = blockIdx.x * blockDim.x + threadIdx.x;
    if (e >= N_EDGES) return;
    int src = ei[e];
    int dst = ei[N_EDGES + e];
    float in[10];
    const float* xi = x + (long)dst * DIM;
    const float* xj = x + (long)src * DIM;
#pragma unroll
    for (int d = 0; d < DIM; ++d) in[d] = xi[d];
#pragma unroll
    for (int d = 0; d < DIM; ++d) in[DIM + d] = xj[d];
    float msg[DIM];
#pragma unroll
    for (int j = 0; j < DIM; ++j) msg[j] = b2[j];
#pragma unroll 8
    for (int h = 0; h < HID; ++h) {
        float acc = b1[h];
#pragma unroll
        for (int d = 0; d < 10; ++d) acc = fmaf(in[d], W1[d * HID + h], acc);
        acc = fmaxf(acc, 0.0f);
#pragma unroll
        for (int j = 0; j < DIM; ++j) msg[j] = fmaf(acc, W2[h * DIM + j], msg[j]);
    }
    float* ap = aggr + (long)dst * DIM;
#pragma unroll
    for (int j = 0; j < DIM; ++j) atomicAdd(ap + j, msg[j]);
}

template <bool FINAL>
__global__ __launch_bounds__(256) void node_upd_kernel(
    const float* __restrict__ x, const float* __restrict__ aggr,
    const float* __restrict__ U1, const float* __restrict__ bu1,
    const float* __restrict__ U2, const float* __restrict__ bu2,
    const float* __restrict__ Wr, const float* __restrict__ br,
    float* __restrict__ xout)
{
    int v = blockIdx.x * blockDim.x + threadIdx.x;
    if (v >= N_NODES) return;
    float in[10];
#pragma unroll
    for (int d = 0; d < DIM; ++d) in[d] = x[(long)v * DIM + d];
#pragma unroll
    for (int d = 0; d < DIM; ++d) in[DIM + d] = aggr[(long)v * DIM + d];
    float upd[DIM];
#pragma unroll
    for (int j = 0; j < DIM; ++j) upd[j] = bu2[j];
#pragma unroll 8
    for (int h = 0; h < HID; ++h) {
        float acc = bu1[h];
#pragma unroll
        for (int d = 0; d < 10; ++d) acc = fmaf(in[d], U1[d * HID + h], acc);
        acc = fmaxf(acc, 0.0f);
#pragma unroll
        for (int j = 0; j < DIM; ++j) upd[j] = fmaf(acc, U2[h * DIM + j], upd[j]);
    }
    float xn[DIM];
#pragma unroll
    for (int j = 0; j < DIM; ++j) xn[j] = upd[j] + in[j];
    if (FINAL) {
#pragma unroll
        for (int j = 0; j < DIM; ++j) {
            float o = br[j];
#pragma unroll
            for (int d = 0; d < DIM; ++d) o = fmaf(xn[d], Wr[d * DIM + j], o);
            xout[(long)v * DIM + j] = o;
        }
    } else {
#pragma unroll
        for (int j = 0; j < DIM; ++j) xout[(long)v * DIM + j] = xn[j];
    }
}

// ================= launch =================

static inline size_t alignup(size_t x) { return (x + 255) & ~(size_t)255; }

extern "C" void kernel_launch(void* const* d_in, const int* in_sizes, int n_in,
                              void* d_out, int out_size, void* d_ws, size_t ws_size,
                              hipStream_t stream) {
    const float* x   = (const float*)d_in[0];
    const int*   ei  = (const int*)d_in[1];
    const float* W1  = (const float*)d_in[2];
    const float* b1  = (const float*)d_in[3];
    const float* W2  = (const float*)d_in[4];
    const float* b2  = (const float*)d_in[5];
    const float* U1  = (const float*)d_in[6];
    const float* bu1 = (const float*)d_in[7];
    const float* U2  = (const float*)d_in[8];
    const float* bu2 = (const float*)d_in[9];
    const float* Wr  = (const float*)d_in[10];
    const float* br  = (const float*)d_in[11];
    float* out = (float*)d_out;

    char* ws = (char*)d_ws;

    // workspace layout
    size_t o_cnt  = 0;
    size_t o_row  = alignup(o_cnt + (size_t)N_NODES * 4);
    size_t o_bsum = alignup(o_row + (size_t)(N_NODES + 1) * 4);
    size_t o_bpre = alignup(o_bsum + (size_t)NBLK * 4);
    size_t o_sp   = alignup(o_bpre + (size_t)NBLK * 4);        // int2 pairs 12.8 MB
    size_t o_perm = alignup(o_sp + (size_t)N_EDGES * 8);       // eperm 6.4 MB
    size_t o_rank = alignup(o_perm + (size_t)N_EDGES * 4);     // rank 6.4 MB
    size_t o_xA   = alignup(o_rank + (size_t)N_EDGES * 4);
    size_t o_xB   = alignup(o_xA + (size_t)N_NODES * DIM * 4);
    size_t o_msg  = alignup(o_xB + (size_t)N_NODES * DIM * 4); // msg 32 MB
    size_t needed = o_msg + (size_t)N_EDGES * DIM * 4;

    dim3 blk(256);
    dim3 eg((N_EDGES + 255) / 256);
    dim3 ng((N_NODES + 255) / 256);
    dim3 ng8((N_NODES * 8 + 255) / 256);   // 3125 blocks, exact

    if (ws_size < needed) {
        // fallback: atomic scatter path (proven correct)
        size_t nbytes = (size_t)N_NODES * DIM * sizeof(float);
        float* aggr = (float*)ws;
        float* xA   = (float*)(ws + nbytes);
        float* xB   = (float*)(ws + 2 * nbytes);
        const float* xcur = x;
        for (int l = 0; l < N_LAYERS; ++l) {
            hipMemsetAsync(aggr, 0, nbytes, stream);
            edge_msg_kernel<<<eg, blk, 0, stream>>>(
                xcur, ei, W1 + l * 10 * HID, b1 + l * HID,
                W2 + l * HID * DIM, b2 + l * DIM, aggr);
            if (l < N_LAYERS - 1) {
                float* xn = (l == 0) ? xA : xB;
                node_upd_kernel<false><<<ng, blk, 0, stream>>>(
                    xcur, aggr, U1 + l * 10 * HID, bu1 + l * HID,
                    U2 + l * HID * DIM, bu2 + l * DIM, Wr, br, xn);
                xcur = xn;
            } else {
                node_upd_kernel<true><<<ng, blk, 0, stream>>>(
                    xcur, aggr, U1 + l * 10 * HID, bu1 + l * HID,
                    U2 + l * HID * DIM, bu2 + l * DIM, Wr, br, out);
            }
        }
        return;
    }

    int* cnt      = (int*)(ws + o_cnt);
    int* row_ptr  = (int*)(ws + o_row);
    int* blk_sum  = (int*)(ws + o_bsum);
    int* blk_pref = (int*)(ws + o_bpre);
    int2* spair   = (int2*)(ws + o_sp);
    int* eperm    = (int*)(ws + o_perm);
    int* rank     = (int*)(ws + o_rank);
    float* xA     = (float*)(ws + o_xA);
    float* xB     = (float*)(ws + o_xB);
    float* msgbuf = (float*)(ws + o_msg);

    // ---- fused: histogram + layer-1 messages (original order) ----
    hipMemsetAsync(cnt, 0, (size_t)N_NODES * 4, stream);
    fused_hist_msg1_kernel<<<eg, blk, 0, stream>>>(
        x, ei, W1, b1, W2, b2, cnt, rank, msgbuf);

    // ---- CSR scan + scatter ----
    scan_part_kernel<<<NBLK, SCAN_BLK, 0, stream>>>(cnt, blk_sum);
    scan_blk_kernel<<<1, 512, 0, stream>>>(blk_sum, blk_pref);
    scan_add_kernel<<<NBLK, SCAN_BLK, 0, stream>>>(cnt, blk_pref, row_ptr);
    scatter_pair_perm_kernel<<<eg, blk, 0, stream>>>(ei, rank, row_ptr, spair, eperm);

    // ---- layer 1: gather msg0 via eperm + update ----
    gather_update8_kernel<false, true><<<ng8, blk, 0, stream>>>(
        x, msgbuf, eperm, row_ptr, U1, bu1, U2, bu2, Wr, br, xA);

    // ---- layer 2 ----
    edge_msg_sorted_kernel<<<eg, blk, 0, stream>>>(
        xA, spair, W1 + 10 * HID, b1 + HID,
        W2 + HID * DIM, b2 + DIM, msgbuf);
    gather_update8_kernel<false, false><<<ng8, blk, 0, stream>>>(
        xA, msgbuf, nullptr, row_ptr, U1 + 10 * HID, bu1 + HID,
        U2 + HID * DIM, bu2 + DIM, Wr, br, xB);

    // ---- layer 3 (+ readout) ----
    edge_msg_sorted_kernel<<<eg, blk, 0, stream>>>(
        xB, spair, W1 + 2 * 10 * HID, b1 + 2 * HID,
        W2 + 2 * HID * DIM, b2 + 2 * DIM, msgbuf);
    gather_update8_kernel<true, false><<<ng8, blk, 0, stream>>>(
        xB, msgbuf, nullptr, row_ptr, U1 + 2 * 10 * HID, bu1 + 2 * HID,
        U2 + 2 * HID * DIM, bu2 + 2 * DIM, Wr, br, out);
}